// Round 1
// 438.203 us; speedup vs baseline: 1.0809x; 1.0809x over previous
//
#include <hip/hip_runtime.h>
#include <hip/hip_bf16.h>

typedef __bf16 bf16_t;
typedef __attribute__((ext_vector_type(8))) __bf16 bf16x8;
typedef __attribute__((ext_vector_type(4))) float f32x4;

#define MFMA(a, b, c) __builtin_amdgcn_mfma_f32_16x16x32_bf16(a, b, c, 0, 0, 0)

// Async global->LDS, 16B per lane. Dest = wave-uniform base + lane*16 (measured m104).
__device__ inline void gload_lds16(const bf16_t* g, bf16_t* l) {
  __builtin_amdgcn_global_load_lds(
      (const __attribute__((address_space(1))) void*)g,
      (__attribute__((address_space(3))) void*)l, 16, 0, 0);
}

// Diagnostic sentinel (fp32 output): absmax ~= val identifies the guard.
__global__ void fill_sentinel(float* out, int n, float val) {
  int i = blockIdx.x * blockDim.x + threadIdx.x;
  if (i < n) out[i] = val;
}

// Weights fp32 W[h][d][kk] (3 matrices) -> Wt bf16 [m][(h*64+kk)][d]
__global__ void transpose_w(const float* __restrict__ Wq, const float* __restrict__ Wk,
                            const float* __restrict__ Wv, bf16_t* __restrict__ Wt) {
  int gid = blockIdx.x * blockDim.x + threadIdx.x;
  int e = gid * 8;
  int m = e >> 20;
  int rem = e & 1048575;
  int n = rem >> 10;               // h*64+kk
  int d0 = rem & 1023;
  const float* W = (m == 0) ? Wq : (m == 1) ? Wk : Wv;
  int h = n >> 6, kk = n & 63;
  union { bf16_t h8[8]; uint4 u; } tmp;
#pragma unroll
  for (int j = 0; j < 8; ++j)
    tmp.h8[j] = (bf16_t)W[((size_t)(h * 1024 + d0 + j)) * 64 + kk];
  *(uint4*)(Wt + e) = tmp.u;
}

// Vectorized fp32 -> bf16 cast, 8 elems/thread, exact grid (no bounds check).
__global__ void cvt_bf16(const float* __restrict__ in, bf16_t* __restrict__ out) {
  size_t i = (size_t)(blockIdx.x * blockDim.x + threadIdx.x) * 8;
  f32x4 a = *(const f32x4*)(in + i);
  f32x4 b = *(const f32x4*)(in + i + 4);
  bf16x8 r;
  r[0] = (bf16_t)a[0]; r[1] = (bf16_t)a[1]; r[2] = (bf16_t)a[2]; r[3] = (bf16_t)a[3];
  r[4] = (bf16_t)b[0]; r[5] = (bf16_t)b[1]; r[6] = (bf16_t)b[2]; r[7] = (bf16_t)b[3];
  *(bf16x8*)(out + i) = r;
}

// C = A[M,K] * Bt[N,K]^T, all-bf16 inputs, m97-style global_load_lds staging.
// MODE 0: out bf16 [h][b][s][dk]; MODE 1: out bf16 [h][b][dk][s];
// MODE 2: out fp32 [M,N] + bias.
template <int MODE>
__global__ void gemm_bt(const bf16_t* __restrict__ A, const bf16_t* __restrict__ Bt,
                        const float* __restrict__ bias, void* __restrict__ out_,
                        int M, int N, int K) {
  // Linear LDS (global_load_lds requires contiguous dest): [128 rows][32 elems].
  __shared__ bf16_t sA[128 * 32];
  __shared__ bf16_t sB[128 * 32];
  const int t = threadIdx.x;
  const int w = t >> 6, l = t & 63;
  const int lq = l >> 4, ll = l & 15;
  const int m0 = blockIdx.x * 128, n0 = blockIdx.y * 128;
  const int wr = (w >> 1) * 64, wc = (w & 1) * 64;
  // Staging: chunk ch = w*2+c covers rows [ch*16, ch*16+16); lane l lands at
  // chunk_base + l*16B -> row = ch*16 + l/4, col = (l&3)*8 elems.
  const int srow = l >> 2;
  const int scol = (l & 3) * 8;
  f32x4 acc[4][4] = {};
  for (int k0 = 0; k0 < K; k0 += 32) {
    __syncthreads();   // prior ds_reads done before overwrite
#pragma unroll
    for (int c = 0; c < 2; ++c) {
      int ch = w * 2 + c;
      int row = ch * 16 + srow;
      gload_lds16(A  + (size_t)(m0 + row) * K + k0 + scol, sA + ch * 512);
      gload_lds16(Bt + (size_t)(n0 + row) * K + k0 + scol, sB + ch * 512);
    }
    __syncthreads();   // implicit vmcnt(0) drains global_load_lds
    bf16x8 af[4], bfr[4];
#pragma unroll
    for (int i = 0; i < 4; ++i) {
      af[i]  = *(const bf16x8*)(sA + (wr + i * 16 + ll) * 32 + lq * 8);
      bfr[i] = *(const bf16x8*)(sB + (wc + i * 16 + ll) * 32 + lq * 8);
    }
#pragma unroll
    for (int mi = 0; mi < 4; ++mi)
#pragma unroll
      for (int ni = 0; ni < 4; ++ni)
        acc[mi][ni] = MFMA(af[mi], bfr[ni], acc[mi][ni]);
  }
  // D layout: col=lane&15, row=(lane>>4)*4+reg (measured m89/m91).
#pragma unroll
  for (int mi = 0; mi < 4; ++mi)
#pragma unroll
    for (int ni = 0; ni < 4; ++ni)
#pragma unroll
      for (int r = 0; r < 4; ++r) {
        int row = m0 + wr + mi * 16 + lq * 4 + r;
        int col = n0 + wc + ni * 16 + ll;
        float v = acc[mi][ni][r];
        if (MODE == 2) {
          ((float*)out_)[(size_t)row * N + col] = v + bias[col];
        } else {
          int h = col >> 6, kk = col & 63, b = row >> 10, s = row & 1023;
          size_t idx;
          if (MODE == 0)
            idx = ((size_t)((h * 8 + b) * 1024 + s)) * 64 + kk;
          else
            idx = ((size_t)((h * 8 + b) * 64 + kk)) * 1024 + s;
          ((bf16_t*)out_)[idx] = (bf16_t)v;
        }
      }
}

// Flash attention. qh/kh: [h][b][s][dk], vt: [h][b][dk][s], c out: [b][s][h*64+dk].
// Block: 64 q-rows for one (h,b). 4 waves, each owns 16 q-rows.
// Value-verified against the scalar fp32 reference (rounds 2-5 agree to ~0.002).
__global__ void attn_kernel(const bf16_t* __restrict__ qh, const bf16_t* __restrict__ kh,
                            const bf16_t* __restrict__ vt, bf16_t* __restrict__ c) {
  constexpr int QP = 72, KP = 72, VP = 136, PP = 136;
  __shared__ bf16_t sQ[64 * QP];
  __shared__ bf16_t sK[128 * KP];
  __shared__ bf16_t sV[64 * VP];
  __shared__ bf16_t sP[4][16 * PP];
  const int t = threadIdx.x;
  const int w = t >> 6, l = t & 63;
  const int lq = l >> 4, ll = l & 15;
  const int q0 = blockIdx.x * 64;
  const int hb = blockIdx.y;          // h*8+b
  const int h = hb >> 3, b = hb & 7;
  const size_t base = (size_t)hb * 65536;
  const bf16_t* Q = qh + base + (size_t)q0 * 64;
  const bf16_t* K = kh + base;
  const bf16_t* V = vt + base;        // [64][1024]
#pragma unroll
  for (int r = 0; r < 2; ++r) {
    int e = (r * 256 + t) * 8;
    int row = e >> 6, col = e & 63;
    *(uint4*)(sQ + row * QP + col) = *(const uint4*)(Q + e);
  }
  float mrow[4], lrow[4];
  f32x4 o[4] = {};
#pragma unroll
  for (int r = 0; r < 4; ++r) { mrow[r] = -1e30f; lrow[r] = 0.f; }

  for (int kt = 0; kt < 1024; kt += 128) {
    __syncthreads();
#pragma unroll
    for (int r = 0; r < 4; ++r) {
      int e = (r * 256 + t) * 8;
      int row = e >> 6, col = e & 63;
      *(uint4*)(sK + row * KP + col) = *(const uint4*)(K + (size_t)kt * 64 + e);
      int rowv = e >> 7, colv = e & 127;
      *(uint4*)(sV + rowv * VP + colv) =
          *(const uint4*)(V + (size_t)rowv * 1024 + kt + colv);
    }
    __syncthreads();
    f32x4 sacc[8] = {};
    bf16x8 aq[2];
#pragma unroll
    for (int ks = 0; ks < 2; ++ks)
      aq[ks] = *(const bf16x8*)(sQ + (w * 16 + ll) * QP + ks * 32 + lq * 8);
#pragma unroll
    for (int ni = 0; ni < 8; ++ni)
#pragma unroll
      for (int ks = 0; ks < 2; ++ks) {
        bf16x8 bk = *(const bf16x8*)(sK + (ni * 16 + ll) * KP + ks * 32 + lq * 8);
        sacc[ni] = MFMA(aq[ks], bk, sacc[ni]);
      }
    float rmax[4] = {-1e30f, -1e30f, -1e30f, -1e30f};
#pragma unroll
    for (int ni = 0; ni < 8; ++ni)
#pragma unroll
      for (int r = 0; r < 4; ++r) {
        sacc[ni][r] *= 0.125f;
        rmax[r] = fmaxf(rmax[r], sacc[ni][r]);
      }
#pragma unroll
    for (int off = 1; off < 16; off <<= 1)
#pragma unroll
      for (int r = 0; r < 4; ++r)
        rmax[r] = fmaxf(rmax[r], __shfl_xor(rmax[r], off));
    float alpha[4];
#pragma unroll
    for (int r = 0; r < 4; ++r) {
      float mnew = fmaxf(mrow[r], rmax[r]);
      alpha[r] = __expf(mrow[r] - mnew);
      mrow[r] = mnew;
    }
    float rs[4] = {0.f, 0.f, 0.f, 0.f};
#pragma unroll
    for (int ni = 0; ni < 8; ++ni)
#pragma unroll
      for (int r = 0; r < 4; ++r) {
        float p = __expf(sacc[ni][r] - mrow[r]);
        sacc[ni][r] = p;
        rs[r] += p;
      }
#pragma unroll
    for (int off = 1; off < 16; off <<= 1)
#pragma unroll
      for (int r = 0; r < 4; ++r)
        rs[r] += __shfl_xor(rs[r], off);
#pragma unroll
    for (int r = 0; r < 4; ++r)
      lrow[r] = lrow[r] * alpha[r] + rs[r];
#pragma unroll
    for (int ni = 0; ni < 4; ++ni)
#pragma unroll
      for (int r = 0; r < 4; ++r)
        o[ni][r] *= alpha[r];
    bf16_t* Pw = sP[w];
#pragma unroll
    for (int ni = 0; ni < 8; ++ni)
#pragma unroll
      for (int r = 0; r < 4; ++r)
        Pw[(lq * 4 + r) * PP + ni * 16 + ll] = (bf16_t)sacc[ni][r];
    asm volatile("s_waitcnt lgkmcnt(0)" ::: "memory");
#pragma unroll
    for (int ks = 0; ks < 4; ++ks) {
      bf16x8 ap = *(const bf16x8*)(Pw + ll * PP + ks * 32 + lq * 8);
#pragma unroll
      for (int ni = 0; ni < 4; ++ni) {
        bf16x8 bv = *(const bf16x8*)(sV + (ni * 16 + ll) * VP + ks * 32 + lq * 8);
        o[ni] = MFMA(ap, bv, o[ni]);
      }
    }
  }
#pragma unroll
  for (int ni = 0; ni < 4; ++ni)
#pragma unroll
    for (int r = 0; r < 4; ++r) {
      int s = q0 + w * 16 + lq * 4 + r;
      int dk = ni * 16 + ll;
      float val = o[ni][r] / lrow[r];
      c[((size_t)(b * 1024 + s)) * 1024 + h * 64 + dk] = (bf16_t)val;
    }
}

extern "C" void kernel_launch(void* const* d_in, const int* in_sizes, int n_in,
                              void* d_out, int out_size, void* d_ws, size_t ws_size,
                              hipStream_t stream) {
  float* out = (float*)d_out;   // reference output dtype is fp32!
  int nblk_out = (out_size + 255) / 256;
  if (n_in != 8) {
    fill_sentinel<<<nblk_out, 256, 0, stream>>>(out, out_size, 600.0f + 10.0f * n_in);
    return;
  }
  const int expect[8] = {8388608, 8388608, 8388608, 1048576,
                         1048576, 1048576, 1048576, 1024};
  for (int i = 0; i < 8; ++i)
    if (in_sizes[i] != expect[i]) {
      fill_sentinel<<<nblk_out, 256, 0, stream>>>(out, out_size, 500.0f + 10.0f * i);
      return;
    }

  // ws map (bf16 elems): qh [0,8M) | kh [8M,16M) | vt [16M,24M) | Wt/cbuf [24M,32M)
  bf16_t* ws   = (bf16_t*)d_ws;
  bf16_t* qhb  = ws;
  bf16_t* khb  = ws + 8388608;
  bf16_t* vtb  = ws + 16777216;
  bf16_t* Wt   = ws + 25165824;
  bf16_t* cbuf = ws + 25165824;   // overlaps Wt (dead after projections)
  bf16_t* Wob  = ws;              // overlaps qhb (dead after attn)
  if (ws_size < 67108864ull) {
    fill_sentinel<<<nblk_out, 256, 0, stream>>>(out, out_size, 400.0f);
    return;
  }

  const float* q  = (const float*)d_in[0];
  const float* k  = (const float*)d_in[1];
  const float* v  = (const float*)d_in[2];
  const float* Wq = (const float*)d_in[3];
  const float* Wk = (const float*)d_in[4];
  const float* Wv = (const float*)d_in[5];
  const float* Wo = (const float*)d_in[6];
  const float* bo = (const float*)d_in[7];

  // d_out (32MB) doubles as bf16 scratch until the final GEMM:
  //   qb [0,8M elems) , kb [8M,16M) ; vb reuses [0,8M) once qb is consumed.
  bf16_t* qb = (bf16_t*)d_out;
  bf16_t* kb = (bf16_t*)d_out + 8388608;
  bf16_t* vb = (bf16_t*)d_out;

  transpose_w<<<1536, 256, 0, stream>>>(Wq, Wk, Wv, Wt);
  cvt_bf16<<<4096, 256, 0, stream>>>(q, qb);
  cvt_bf16<<<4096, 256, 0, stream>>>(k, kb);
  dim3 gg(64, 8);
  gemm_bt<0><<<gg, 256, 0, stream>>>(qb, Wt,           nullptr, qhb, 8192, 1024, 1024);
  gemm_bt<0><<<gg, 256, 0, stream>>>(kb, Wt + 1048576, nullptr, khb, 8192, 1024, 1024);
  cvt_bf16<<<4096, 256, 0, stream>>>(v, vb);
  gemm_bt<1><<<gg, 256, 0, stream>>>(vb, Wt + 2097152, nullptr, vtb, 8192, 1024, 1024);
  attn_kernel<<<dim3(16, 128), 256, 0, stream>>>(qhb, khb, vtb, cbuf);
  cvt_bf16<<<512, 256, 0, stream>>>(Wo, Wob);
  gemm_bt<2><<<gg, 256, 0, stream>>>(cbuf, Wob, bo, out, 8192, 1024, 1024);
}

// Round 2
// 431.435 us; speedup vs baseline: 1.0979x; 1.0157x over previous
//
#include <hip/hip_runtime.h>
#include <hip/hip_bf16.h>

typedef __bf16 bf16_t;
typedef __attribute__((ext_vector_type(8))) __bf16 bf16x8;
typedef __attribute__((ext_vector_type(4))) float f32x4;

#define MFMA(a, b, c) __builtin_amdgcn_mfma_f32_16x16x32_bf16(a, b, c, 0, 0, 0)

// Async global->LDS, 16B per lane. Dest = wave-uniform base + lane*16 (measured m104).
__device__ inline void gload_lds16(const bf16_t* g, bf16_t* l) {
  __builtin_amdgcn_global_load_lds(
      (const __attribute__((address_space(1))) void*)g,
      (__attribute__((address_space(3))) void*)l, 16, 0, 0);
}

// Diagnostic sentinel (fp32 output): absmax ~= val identifies the guard.
__global__ void fill_sentinel(float* out, int n, float val) {
  int i = blockIdx.x * blockDim.x + threadIdx.x;
  if (i < n) out[i] = val;
}

// Weights fp32 W[h][d][kk] (3 matrices) -> Wt bf16 [m][(h*64+kk)][d]
__global__ void transpose_w(const float* __restrict__ Wq, const float* __restrict__ Wk,
                            const float* __restrict__ Wv, bf16_t* __restrict__ Wt) {
  int gid = blockIdx.x * blockDim.x + threadIdx.x;
  int e = gid * 8;
  int m = e >> 20;
  int rem = e & 1048575;
  int n = rem >> 10;               // h*64+kk
  int d0 = rem & 1023;
  const float* W = (m == 0) ? Wq : (m == 1) ? Wk : Wv;
  int h = n >> 6, kk = n & 63;
  union { bf16_t h8[8]; uint4 u; } tmp;
#pragma unroll
  for (int j = 0; j < 8; ++j)
    tmp.h8[j] = (bf16_t)W[((size_t)(h * 1024 + d0 + j)) * 64 + kk];
  *(uint4*)(Wt + e) = tmp.u;
}

// Vectorized fp32 -> bf16 cast, 8 elems/thread, exact grid (no bounds check).
__global__ void cvt_bf16(const float* __restrict__ in, bf16_t* __restrict__ out) {
  size_t i = (size_t)(blockIdx.x * blockDim.x + threadIdx.x) * 8;
  f32x4 a = *(const f32x4*)(in + i);
  f32x4 b = *(const f32x4*)(in + i + 4);
  bf16x8 r;
  r[0] = (bf16_t)a[0]; r[1] = (bf16_t)a[1]; r[2] = (bf16_t)a[2]; r[3] = (bf16_t)a[3];
  r[4] = (bf16_t)b[0]; r[5] = (bf16_t)b[1]; r[6] = (bf16_t)b[2]; r[7] = (bf16_t)b[3];
  *(bf16x8*)(out + i) = r;
}

// C = A[M,K] * Bt[N,K]^T, all-bf16 inputs, m97-style global_load_lds staging.
// MODE 0: out bf16 [h][b][s][dk]; MODE 1: out bf16 [h][b][dk][s];
// MODE 2: out fp32 [M,N] + bias.  scale applied in MODE 0/1 epilogue.
template <int MODE>
__global__ void gemm_bt(const bf16_t* __restrict__ A, const bf16_t* __restrict__ Bt,
                        const float* __restrict__ bias, void* __restrict__ out_,
                        int M, int N, int K, float scale) {
  // Linear LDS (global_load_lds requires contiguous dest): [128 rows][32 elems].
  __shared__ bf16_t sA[128 * 32];
  __shared__ bf16_t sB[128 * 32];
  const int t = threadIdx.x;
  const int w = t >> 6, l = t & 63;
  const int lq = l >> 4, ll = l & 15;
  const int m0 = blockIdx.x * 128, n0 = blockIdx.y * 128;
  const int wr = (w >> 1) * 64, wc = (w & 1) * 64;
  // Staging: chunk ch = w*2+c covers rows [ch*16, ch*16+16); lane l lands at
  // chunk_base + l*16B -> row = ch*16 + l/4, col = (l&3)*8 elems.
  const int srow = l >> 2;
  const int scol = (l & 3) * 8;
  f32x4 acc[4][4] = {};
  for (int k0 = 0; k0 < K; k0 += 32) {
    __syncthreads();   // prior ds_reads done before overwrite
#pragma unroll
    for (int c = 0; c < 2; ++c) {
      int ch = w * 2 + c;
      int row = ch * 16 + srow;
      gload_lds16(A  + (size_t)(m0 + row) * K + k0 + scol, sA + ch * 512);
      gload_lds16(Bt + (size_t)(n0 + row) * K + k0 + scol, sB + ch * 512);
    }
    __syncthreads();   // implicit vmcnt(0) drains global_load_lds
    bf16x8 af[4], bfr[4];
#pragma unroll
    for (int i = 0; i < 4; ++i) {
      af[i]  = *(const bf16x8*)(sA + (wr + i * 16 + ll) * 32 + lq * 8);
      bfr[i] = *(const bf16x8*)(sB + (wc + i * 16 + ll) * 32 + lq * 8);
    }
#pragma unroll
    for (int mi = 0; mi < 4; ++mi)
#pragma unroll
      for (int ni = 0; ni < 4; ++ni)
        acc[mi][ni] = MFMA(af[mi], bfr[ni], acc[mi][ni]);
  }
  // D layout: col=lane&15, row=(lane>>4)*4+reg (measured m89/m91).
#pragma unroll
  for (int mi = 0; mi < 4; ++mi)
#pragma unroll
    for (int ni = 0; ni < 4; ++ni)
#pragma unroll
      for (int r = 0; r < 4; ++r) {
        int row = m0 + wr + mi * 16 + lq * 4 + r;
        int col = n0 + wc + ni * 16 + ll;
        float v = acc[mi][ni][r];
        if (MODE == 2) {
          ((float*)out_)[(size_t)row * N + col] = v + bias[col];
        } else {
          int h = col >> 6, kk = col & 63, b = row >> 10, s = row & 1023;
          size_t idx;
          if (MODE == 0)
            idx = ((size_t)((h * 8 + b) * 1024 + s)) * 64 + kk;
          else
            idx = ((size_t)((h * 8 + b) * 64 + kk)) * 1024 + s;
          ((bf16_t*)out_)[idx] = (bf16_t)(v * scale);
        }
      }
}

// Flash attention v2. qh (PRE-SCALED by 1/8): [h][b][s][dk], kh: [h][b][s][dk],
// vt: [h][b][dk][s], c out: [b][s][h*64+dk].
// Block: 64 q-rows for one (h,b). 4 waves, each owns 16 q-rows.
// Changes vs v1 (round-1): 64-key tiles, no V staging (V L2-resident, read in PV),
// defer-max rescale (T13, THR=8), scale folded into Q projection.
// LDS 27.6KB -> 5 blocks/CU.
__global__ void attn_kernel(const bf16_t* __restrict__ qh, const bf16_t* __restrict__ kh,
                            const bf16_t* __restrict__ vt, bf16_t* __restrict__ c) {
  constexpr int QP = 72, KP = 72, PP = 72;
  __shared__ bf16_t sQ[64 * QP];
  __shared__ bf16_t sK[64 * KP];
  __shared__ bf16_t sP[4][16 * PP];
  const int t = threadIdx.x;
  const int w = t >> 6, l = t & 63;
  const int lq = l >> 4, ll = l & 15;
  const int q0 = blockIdx.x * 64;
  const int hb = blockIdx.y;          // h*8+b
  const int h = hb >> 3, b = hb & 7;
  const size_t base = (size_t)hb * 65536;
  const bf16_t* Q = qh + base + (size_t)q0 * 64;
  const bf16_t* K = kh + base;
  const bf16_t* V = vt + base;        // [64][1024]
#pragma unroll
  for (int r = 0; r < 2; ++r) {
    int e = (r * 256 + t) * 8;
    int row = e >> 6, col = e & 63;
    *(uint4*)(sQ + row * QP + col) = *(const uint4*)(Q + e);
  }
  float mrow[4], lrow[4];
  f32x4 o[4] = {};
#pragma unroll
  for (int r = 0; r < 4; ++r) { mrow[r] = -1e30f; lrow[r] = 0.f; }

  for (int kt = 0; kt < 1024; kt += 64) {
    __syncthreads();
    // Stage K tile: 64 rows x 64 cols, 2 uint4 per thread.
#pragma unroll
    for (int r = 0; r < 2; ++r) {
      int e = (r * 256 + t) * 8;
      int row = e >> 6, col = e & 63;
      *(uint4*)(sK + row * KP + col) = *(const uint4*)(K + (size_t)kt * 64 + e);
    }
    __syncthreads();
    // QK^T: S[q=lq*4+r (+w*16)][key=16ni+ll]
    f32x4 sacc[4] = {};
    bf16x8 aq[2];
#pragma unroll
    for (int ks = 0; ks < 2; ++ks)
      aq[ks] = *(const bf16x8*)(sQ + (w * 16 + ll) * QP + ks * 32 + lq * 8);
#pragma unroll
    for (int ni = 0; ni < 4; ++ni)
#pragma unroll
      for (int ks = 0; ks < 2; ++ks) {
        bf16x8 bk = *(const bf16x8*)(sK + (ni * 16 + ll) * KP + ks * 32 + lq * 8);
        sacc[ni] = MFMA(aq[ks], bk, sacc[ni]);
      }
    // Row max (Q pre-scaled, no 0.125 here).
    float rmax[4] = {-1e30f, -1e30f, -1e30f, -1e30f};
#pragma unroll
    for (int ni = 0; ni < 4; ++ni)
#pragma unroll
      for (int r = 0; r < 4; ++r)
        rmax[r] = fmaxf(rmax[r], sacc[ni][r]);
#pragma unroll
    for (int off = 1; off < 16; off <<= 1)
#pragma unroll
      for (int r = 0; r < 4; ++r)
        rmax[r] = fmaxf(rmax[r], __shfl_xor(rmax[r], off));
    // T13 defer-max: skip O/l rescale while max growth <= 8 (P bounded by e^8).
    bool ok = true;
#pragma unroll
    for (int r = 0; r < 4; ++r)
      ok = ok && (rmax[r] <= mrow[r] + 8.0f);
    if (!__all(ok)) {
#pragma unroll
      for (int r = 0; r < 4; ++r) {
        float mnew = fmaxf(mrow[r], rmax[r]);
        float alpha = __expf(mrow[r] - mnew);
        mrow[r] = mnew;
        lrow[r] *= alpha;
#pragma unroll
        for (int ni = 0; ni < 4; ++ni)
          o[ni][r] *= alpha;
      }
    }
    // P = exp(S - m), row sums.
    float rs[4] = {0.f, 0.f, 0.f, 0.f};
#pragma unroll
    for (int ni = 0; ni < 4; ++ni)
#pragma unroll
      for (int r = 0; r < 4; ++r) {
        float p = __expf(sacc[ni][r] - mrow[r]);
        sacc[ni][r] = p;
        rs[r] += p;
      }
#pragma unroll
    for (int off = 1; off < 16; off <<= 1)
#pragma unroll
      for (int r = 0; r < 4; ++r)
        rs[r] += __shfl_xor(rs[r], off);
#pragma unroll
    for (int r = 0; r < 4; ++r)
      lrow[r] += rs[r];
    // P -> LDS (per-wave buffer, wave-local ordering via lgkmcnt only).
    bf16_t* Pw = sP[w];
#pragma unroll
    for (int ni = 0; ni < 4; ++ni)
#pragma unroll
      for (int r = 0; r < 4; ++r)
        Pw[(lq * 4 + r) * PP + ni * 16 + ll] = (bf16_t)sacc[ni][r];
    asm volatile("s_waitcnt lgkmcnt(0)" ::: "memory");
    // PV: V read straight from global (L2-resident; each elem used once per block).
#pragma unroll
    for (int ks = 0; ks < 2; ++ks) {
      bf16x8 ap = *(const bf16x8*)(Pw + ll * PP + ks * 32 + lq * 8);
#pragma unroll
      for (int ni = 0; ni < 4; ++ni) {
        bf16x8 bv = *(const bf16x8*)(V + (size_t)(ni * 16 + ll) * 1024 + kt + ks * 32 + lq * 8);
        o[ni] = MFMA(ap, bv, o[ni]);
      }
    }
  }
#pragma unroll
  for (int ni = 0; ni < 4; ++ni)
#pragma unroll
    for (int r = 0; r < 4; ++r) {
      int s = q0 + w * 16 + lq * 4 + r;
      int dk = ni * 16 + ll;
      float val = o[ni][r] / lrow[r];
      c[((size_t)(b * 1024 + s)) * 1024 + h * 64 + dk] = (bf16_t)val;
    }
}

extern "C" void kernel_launch(void* const* d_in, const int* in_sizes, int n_in,
                              void* d_out, int out_size, void* d_ws, size_t ws_size,
                              hipStream_t stream) {
  float* out = (float*)d_out;   // reference output dtype is fp32!
  int nblk_out = (out_size + 255) / 256;
  if (n_in != 8) {
    fill_sentinel<<<nblk_out, 256, 0, stream>>>(out, out_size, 600.0f + 10.0f * n_in);
    return;
  }
  const int expect[8] = {8388608, 8388608, 8388608, 1048576,
                         1048576, 1048576, 1048576, 1024};
  for (int i = 0; i < 8; ++i)
    if (in_sizes[i] != expect[i]) {
      fill_sentinel<<<nblk_out, 256, 0, stream>>>(out, out_size, 500.0f + 10.0f * i);
      return;
    }

  // ws map (bf16 elems): qh [0,8M) | kh [8M,16M) | vt [16M,24M) | Wt/cbuf [24M,32M)
  bf16_t* ws   = (bf16_t*)d_ws;
  bf16_t* qhb  = ws;
  bf16_t* khb  = ws + 8388608;
  bf16_t* vtb  = ws + 16777216;
  bf16_t* Wt   = ws + 25165824;
  bf16_t* cbuf = ws + 25165824;   // overlaps Wt (dead after projections)
  bf16_t* Wob  = ws;              // overlaps qhb (dead after attn)
  if (ws_size < 67108864ull) {
    fill_sentinel<<<nblk_out, 256, 0, stream>>>(out, out_size, 400.0f);
    return;
  }

  const float* q  = (const float*)d_in[0];
  const float* k  = (const float*)d_in[1];
  const float* v  = (const float*)d_in[2];
  const float* Wq = (const float*)d_in[3];
  const float* Wk = (const float*)d_in[4];
  const float* Wv = (const float*)d_in[5];
  const float* Wo = (const float*)d_in[6];
  const float* bo = (const float*)d_in[7];

  // d_out (32MB) doubles as bf16 scratch until the final GEMM:
  //   qb [0,8M elems) , kb [8M,16M) ; vb reuses [0,8M) once qb is consumed.
  bf16_t* qb = (bf16_t*)d_out;
  bf16_t* kb = (bf16_t*)d_out + 8388608;
  bf16_t* vb = (bf16_t*)d_out;

  transpose_w<<<1536, 256, 0, stream>>>(Wq, Wk, Wv, Wt);
  cvt_bf16<<<4096, 256, 0, stream>>>(q, qb);
  cvt_bf16<<<4096, 256, 0, stream>>>(k, kb);
  dim3 gg(64, 8);
  // Q projection pre-scaled by 1/sqrt(d_k)=0.125 (exact pow2 in bf16).
  gemm_bt<0><<<gg, 256, 0, stream>>>(qb, Wt,           nullptr, qhb, 8192, 1024, 1024, 0.125f);
  gemm_bt<0><<<gg, 256, 0, stream>>>(kb, Wt + 1048576, nullptr, khb, 8192, 1024, 1024, 1.0f);
  cvt_bf16<<<4096, 256, 0, stream>>>(v, vb);
  gemm_bt<1><<<gg, 256, 0, stream>>>(vb, Wt + 2097152, nullptr, vtb, 8192, 1024, 1024, 1.0f);
  attn_kernel<<<dim3(16, 128), 256, 0, stream>>>(qhb, khb, vtb, cbuf);
  cvt_bf16<<<512, 256, 0, stream>>>(Wo, Wob);
  gemm_bt<2><<<gg, 256, 0, stream>>>(cbuf, Wob, bo, out, 8192, 1024, 1024, 1.0f);
}

// Round 3
// 429.237 us; speedup vs baseline: 1.1035x; 1.0051x over previous
//
#include <hip/hip_runtime.h>
#include <hip/hip_bf16.h>

typedef __bf16 bf16_t;
typedef __attribute__((ext_vector_type(8))) __bf16 bf16x8;
typedef __attribute__((ext_vector_type(4))) float f32x4;

#define MFMA(a, b, c) __builtin_amdgcn_mfma_f32_16x16x32_bf16(a, b, c, 0, 0, 0)

// Async global->LDS, 16B per lane. Dest = wave-uniform base + lane*16 (measured m104).
__device__ inline void gload_lds16(const bf16_t* g, bf16_t* l) {
  __builtin_amdgcn_global_load_lds(
      (const __attribute__((address_space(1))) void*)g,
      (__attribute__((address_space(3))) void*)l, 16, 0, 0);
}

// Diagnostic sentinel (fp32 output): absmax ~= val identifies the guard.
__global__ void fill_sentinel(float* out, int n, float val) {
  int i = blockIdx.x * blockDim.x + threadIdx.x;
  if (i < n) out[i] = val;
}

// Weights fp32 W[h][d][kk] (3 matrices) -> Wt bf16 [m][(h*64+kk)][d]
__global__ void transpose_w(const float* __restrict__ Wq, const float* __restrict__ Wk,
                            const float* __restrict__ Wv, bf16_t* __restrict__ Wt) {
  int gid = blockIdx.x * blockDim.x + threadIdx.x;
  int e = gid * 8;
  int m = e >> 20;
  int rem = e & 1048575;
  int n = rem >> 10;               // h*64+kk
  int d0 = rem & 1023;
  const float* W = (m == 0) ? Wq : (m == 1) ? Wk : Wv;
  int h = n >> 6, kk = n & 63;
  union { bf16_t h8[8]; uint4 u; } tmp;
#pragma unroll
  for (int j = 0; j < 8; ++j)
    tmp.h8[j] = (bf16_t)W[((size_t)(h * 1024 + d0 + j)) * 64 + kk];
  *(uint4*)(Wt + e) = tmp.u;
}

// Vectorized fp32 -> bf16 cast, 8 elems/thread, exact grid (no bounds check).
__global__ void cvt_bf16(const float* __restrict__ in, bf16_t* __restrict__ out) {
  size_t i = (size_t)(blockIdx.x * blockDim.x + threadIdx.x) * 8;
  f32x4 a = *(const f32x4*)(in + i);
  f32x4 b = *(const f32x4*)(in + i + 4);
  bf16x8 r;
  r[0] = (bf16_t)a[0]; r[1] = (bf16_t)a[1]; r[2] = (bf16_t)a[2]; r[3] = (bf16_t)a[3];
  r[4] = (bf16_t)b[0]; r[5] = (bf16_t)b[1]; r[6] = (bf16_t)b[2]; r[7] = (bf16_t)b[3];
  *(bf16x8*)(out + i) = r;
}

// C = A[M,K] * Bt[N,K]^T, all-bf16 inputs, m97-style global_load_lds staging.
// MODE 0: out bf16 [h][b][s][dk]; MODE 1: out bf16 [h][b][dk][s];
// MODE 2: out fp32 [M,N] + bias.  scale applied in MODE 0/1 epilogue.
template <int MODE>
__global__ void gemm_bt(const bf16_t* __restrict__ A, const bf16_t* __restrict__ Bt,
                        const float* __restrict__ bias, void* __restrict__ out_,
                        int M, int N, int K, float scale) {
  // Linear LDS (global_load_lds requires contiguous dest): [128 rows][32 elems].
  __shared__ bf16_t sA[128 * 32];
  __shared__ bf16_t sB[128 * 32];
  const int t = threadIdx.x;
  const int w = t >> 6, l = t & 63;
  const int lq = l >> 4, ll = l & 15;
  const int m0 = blockIdx.x * 128, n0 = blockIdx.y * 128;
  const int wr = (w >> 1) * 64, wc = (w & 1) * 64;
  // Staging: chunk ch = w*2+c covers rows [ch*16, ch*16+16); lane l lands at
  // chunk_base + l*16B -> row = ch*16 + l/4, col = (l&3)*8 elems.
  const int srow = l >> 2;
  const int scol = (l & 3) * 8;
  f32x4 acc[4][4] = {};
  for (int k0 = 0; k0 < K; k0 += 32) {
    __syncthreads();   // prior ds_reads done before overwrite
#pragma unroll
    for (int c = 0; c < 2; ++c) {
      int ch = w * 2 + c;
      int row = ch * 16 + srow;
      gload_lds16(A  + (size_t)(m0 + row) * K + k0 + scol, sA + ch * 512);
      gload_lds16(Bt + (size_t)(n0 + row) * K + k0 + scol, sB + ch * 512);
    }
    __syncthreads();   // implicit vmcnt(0) drains global_load_lds
    bf16x8 af[4], bfr[4];
#pragma unroll
    for (int i = 0; i < 4; ++i) {
      af[i]  = *(const bf16x8*)(sA + (wr + i * 16 + ll) * 32 + lq * 8);
      bfr[i] = *(const bf16x8*)(sB + (wc + i * 16 + ll) * 32 + lq * 8);
    }
#pragma unroll
    for (int mi = 0; mi < 4; ++mi)
#pragma unroll
      for (int ni = 0; ni < 4; ++ni)
        acc[mi][ni] = MFMA(af[mi], bfr[ni], acc[mi][ni]);
  }
  // D layout: col=lane&15, row=(lane>>4)*4+reg (measured m89/m91).
#pragma unroll
  for (int mi = 0; mi < 4; ++mi)
#pragma unroll
    for (int ni = 0; ni < 4; ++ni)
#pragma unroll
      for (int r = 0; r < 4; ++r) {
        int row = m0 + wr + mi * 16 + lq * 4 + r;
        int col = n0 + wc + ni * 16 + ll;
        float v = acc[mi][ni][r];
        if (MODE == 2) {
          ((float*)out_)[(size_t)row * N + col] = v + bias[col];
        } else {
          int h = col >> 6, kk = col & 63, b = row >> 10, s = row & 1023;
          size_t idx;
          if (MODE == 0)
            idx = ((size_t)((h * 8 + b) * 1024 + s)) * 64 + kk;
          else
            idx = ((size_t)((h * 8 + b) * 64 + kk)) * 1024 + s;
          ((bf16_t*)out_)[idx] = (bf16_t)(v * scale);
        }
      }
}

// Flash attention v3. qh (PRE-SCALED by 1/8): [h][b][s][dk], kh: [h][b][s][dk],
// vt: [h][b][dk][s], c out: [b][s][h*64+dk].
// Block: 64 q-rows for one (h,b). 4 waves, each owns 16 q-rows.
// v3 changes: (a) XCD-aware swizzle (T1) so all 16 q-tiles of an hb share one
// XCD L2 (per-XCD KV working set = 16 hb x 256KB = 4MB = L2); (b) shuffle-free
// common-path softmax: lane-partial max for the defer-max check, lane-partial
// lrow accumulated locally, row-max shuffle reduce only in the rare rescale
// branch, lrow reduced once at the end.
__global__ void attn_kernel(const bf16_t* __restrict__ qh, const bf16_t* __restrict__ kh,
                            const bf16_t* __restrict__ vt, bf16_t* __restrict__ c) {
  constexpr int QP = 72, KP = 72, PP = 72;
  __shared__ bf16_t sQ[64 * QP];
  __shared__ bf16_t sK[64 * KP];
  __shared__ bf16_t sP[4][16 * PP];
  const int t = threadIdx.x;
  const int w = t >> 6, l = t & 63;
  const int lq = l >> 4, ll = l & 15;
  // T1 swizzle: orig = x + 16*y, wg = (orig%8)*256 + orig/8 (bijective, 2048%8==0).
  // XCD r processes wg in [r*256,(r+1)*256) = hb in [r*16,(r+1)*16), all q-tiles.
  const int orig = blockIdx.x + (blockIdx.y << 4);
  const int wg = (orig & 7) * 256 + (orig >> 3);
  const int q0 = (wg & 15) * 64;
  const int hb = wg >> 4;             // h*8+b
  const int h = hb >> 3, b = hb & 7;
  const size_t base = (size_t)hb * 65536;
  const bf16_t* Q = qh + base + (size_t)q0 * 64;
  const bf16_t* K = kh + base;
  const bf16_t* V = vt + base;        // [64][1024]
#pragma unroll
  for (int r = 0; r < 2; ++r) {
    int e = (r * 256 + t) * 8;
    int row = e >> 6, col = e & 63;
    *(uint4*)(sQ + row * QP + col) = *(const uint4*)(Q + e);
  }
  float mrow[4], lrow[4];
  f32x4 o[4] = {};
#pragma unroll
  for (int r = 0; r < 4; ++r) { mrow[r] = -1e30f; lrow[r] = 0.f; }

  for (int kt = 0; kt < 1024; kt += 64) {
    __syncthreads();
    // Stage K tile: 64 rows x 64 cols, 2 uint4 per thread.
#pragma unroll
    for (int r = 0; r < 2; ++r) {
      int e = (r * 256 + t) * 8;
      int row = e >> 6, col = e & 63;
      *(uint4*)(sK + row * KP + col) = *(const uint4*)(K + (size_t)kt * 64 + e);
    }
    __syncthreads();
    // QK^T: S[q=lq*4+r (+w*16)][key=16ni+ll]
    f32x4 sacc[4] = {};
    bf16x8 aq[2];
#pragma unroll
    for (int ks = 0; ks < 2; ++ks)
      aq[ks] = *(const bf16x8*)(sQ + (w * 16 + ll) * QP + ks * 32 + lq * 8);
#pragma unroll
    for (int ni = 0; ni < 4; ++ni)
#pragma unroll
      for (int ks = 0; ks < 2; ++ks) {
        bf16x8 bk = *(const bf16x8*)(sK + (ni * 16 + ll) * KP + ks * 32 + lq * 8);
        sacc[ni] = MFMA(aq[ks], bk, sacc[ni]);
      }
    // Lane-partial max (Q pre-scaled). Full row max only needed on rescale.
    float rmax[4] = {-1e30f, -1e30f, -1e30f, -1e30f};
#pragma unroll
    for (int ni = 0; ni < 4; ++ni)
#pragma unroll
      for (int r = 0; r < 4; ++r)
        rmax[r] = fmaxf(rmax[r], sacc[ni][r]);
    // T13 defer-max: per-lane check; __all covers the 16 lanes of each row.
    bool ok = true;
#pragma unroll
    for (int r = 0; r < 4; ++r)
      ok = ok && (rmax[r] <= mrow[r] + 8.0f);
    if (!__all(ok)) {
      // Rare: true row max via shuffle, rescale lane-partial lrow + o.
#pragma unroll
      for (int off = 1; off < 16; off <<= 1)
#pragma unroll
        for (int r = 0; r < 4; ++r)
          rmax[r] = fmaxf(rmax[r], __shfl_xor(rmax[r], off));
#pragma unroll
      for (int r = 0; r < 4; ++r) {
        float mnew = fmaxf(mrow[r], rmax[r]);
        float alpha = __expf(mrow[r] - mnew);  // row-uniform: partials scale OK
        mrow[r] = mnew;
        lrow[r] *= alpha;
#pragma unroll
        for (int ni = 0; ni < 4; ++ni)
          o[ni][r] *= alpha;
      }
    }
    // P = exp(S - m); accumulate lane-partial row sums (no shuffles).
#pragma unroll
    for (int ni = 0; ni < 4; ++ni)
#pragma unroll
      for (int r = 0; r < 4; ++r) {
        float p = __expf(sacc[ni][r] - mrow[r]);
        sacc[ni][r] = p;
        lrow[r] += p;
      }
    // P -> LDS (per-wave buffer, wave-local ordering via lgkmcnt only).
    bf16_t* Pw = sP[w];
#pragma unroll
    for (int ni = 0; ni < 4; ++ni)
#pragma unroll
      for (int r = 0; r < 4; ++r)
        Pw[(lq * 4 + r) * PP + ni * 16 + ll] = (bf16_t)sacc[ni][r];
    asm volatile("s_waitcnt lgkmcnt(0)" ::: "memory");
    // PV: V read straight from global (L2-hot after swizzle).
#pragma unroll
    for (int ks = 0; ks < 2; ++ks) {
      bf16x8 ap = *(const bf16x8*)(Pw + ll * PP + ks * 32 + lq * 8);
#pragma unroll
      for (int ni = 0; ni < 4; ++ni) {
        bf16x8 bv = *(const bf16x8*)(V + (size_t)(ni * 16 + ll) * 1024 + kt + ks * 32 + lq * 8);
        o[ni] = MFMA(ap, bv, o[ni]);
      }
    }
  }
  // Final: reduce lane-partial lrow across the 16 lanes of each row group.
#pragma unroll
  for (int off = 1; off < 16; off <<= 1)
#pragma unroll
    for (int r = 0; r < 4; ++r)
      lrow[r] += __shfl_xor(lrow[r], off);
#pragma unroll
  for (int ni = 0; ni < 4; ++ni)
#pragma unroll
    for (int r = 0; r < 4; ++r) {
      int s = q0 + w * 16 + lq * 4 + r;
      int dk = ni * 16 + ll;
      float val = o[ni][r] / lrow[r];
      c[((size_t)(b * 1024 + s)) * 1024 + h * 64 + dk] = (bf16_t)val;
    }
}

extern "C" void kernel_launch(void* const* d_in, const int* in_sizes, int n_in,
                              void* d_out, int out_size, void* d_ws, size_t ws_size,
                              hipStream_t stream) {
  float* out = (float*)d_out;   // reference output dtype is fp32!
  int nblk_out = (out_size + 255) / 256;
  if (n_in != 8) {
    fill_sentinel<<<nblk_out, 256, 0, stream>>>(out, out_size, 600.0f + 10.0f * n_in);
    return;
  }
  const int expect[8] = {8388608, 8388608, 8388608, 1048576,
                         1048576, 1048576, 1048576, 1024};
  for (int i = 0; i < 8; ++i)
    if (in_sizes[i] != expect[i]) {
      fill_sentinel<<<nblk_out, 256, 0, stream>>>(out, out_size, 500.0f + 10.0f * i);
      return;
    }

  // ws map (bf16 elems): qh [0,8M) | kh [8M,16M) | vt [16M,24M) | Wt/cbuf [24M,32M)
  bf16_t* ws   = (bf16_t*)d_ws;
  bf16_t* qhb  = ws;
  bf16_t* khb  = ws + 8388608;
  bf16_t* vtb  = ws + 16777216;
  bf16_t* Wt   = ws + 25165824;
  bf16_t* cbuf = ws + 25165824;   // overlaps Wt (dead after projections)
  bf16_t* Wob  = ws;              // overlaps qhb (dead after attn)
  if (ws_size < 67108864ull) {
    fill_sentinel<<<nblk_out, 256, 0, stream>>>(out, out_size, 400.0f);
    return;
  }

  const float* q  = (const float*)d_in[0];
  const float* k  = (const float*)d_in[1];
  const float* v  = (const float*)d_in[2];
  const float* Wq = (const float*)d_in[3];
  const float* Wk = (const float*)d_in[4];
  const float* Wv = (const float*)d_in[5];
  const float* Wo = (const float*)d_in[6];
  const float* bo = (const float*)d_in[7];

  // d_out (32MB) doubles as bf16 scratch until the final GEMM:
  //   qb [0,8M elems) , kb [8M,16M) ; vb reuses [0,8M) once qb is consumed.
  bf16_t* qb = (bf16_t*)d_out;
  bf16_t* kb = (bf16_t*)d_out + 8388608;
  bf16_t* vb = (bf16_t*)d_out;

  transpose_w<<<1536, 256, 0, stream>>>(Wq, Wk, Wv, Wt);
  cvt_bf16<<<4096, 256, 0, stream>>>(q, qb);
  cvt_bf16<<<4096, 256, 0, stream>>>(k, kb);
  dim3 gg(64, 8);
  // Q projection pre-scaled by 1/sqrt(d_k)=0.125 (exact pow2 in bf16).
  gemm_bt<0><<<gg, 256, 0, stream>>>(qb, Wt,           nullptr, qhb, 8192, 1024, 1024, 0.125f);
  gemm_bt<0><<<gg, 256, 0, stream>>>(kb, Wt + 1048576, nullptr, khb, 8192, 1024, 1024, 1.0f);
  cvt_bf16<<<4096, 256, 0, stream>>>(v, vb);
  gemm_bt<1><<<gg, 256, 0, stream>>>(vb, Wt + 2097152, nullptr, vtb, 8192, 1024, 1024, 1.0f);
  attn_kernel<<<dim3(16, 128), 256, 0, stream>>>(qhb, khb, vtb, cbuf);
  cvt_bf16<<<512, 256, 0, stream>>>(Wo, Wob);
  gemm_bt<2><<<gg, 256, 0, stream>>>(cbuf, Wob, bo, out, 8192, 1024, 1024, 1.0f);
}